// Round 12
// baseline (91.552 us; speedup 1.0000x reference)
//
#include <hip/hip_runtime.h>
#include <hip/hip_bf16.h>

// SupervisedGraphSage forward via linearity of matmul-over-concat:
//   PQ[i][0:32]  = feat[i] @ W1[:, 0:512].T      (P)
//   PQ[i][32:64] = feat[i] @ W1[:, 512:1024].T   (Q)
//   H1[i] = relu(P[i] + 0.2 * sum_s Q[neigh1[i][s]])
//   comb2[b] = [H1[nodes[b]], 0.2 * sum_s H1[neigh2[b][s]]]
//   out[b] = relu(comb2 @ W2.T) @ Wc.T
//
// R11->R12: k1 moved to gfx950 mfma_f32_16x16x32_f16 (K=32): each step now
// reads a FULL 128B line per feat row (was 64B half-lines), halves MFMA issue
// count and loop iterations; feat loads nontemporal (stream-once). A/B both
// packed with the same slot->k bijection (k = 8*(lane>>4)+j) -> mapping-safe;
// C layout (col=lane&15, row=4*(lane>>4)+reg) is HW-verified and unchanged.
// R11's prefetch + launch_bounds(256,4) reverted (regressed).
// Ledger: k1=42.7 (target), k0~1.5, k2~1, k3~2.5, replay overhead ~22.

#define NFEAT 512
#define NPQ   64
#define HID   32
#define NCLS  40
#define SAMP  5
#define KSTEPS32 (NFEAT / 32)   // 16

typedef float    f32x4 __attribute__((ext_vector_type(4)));
typedef _Float16 f16x4 __attribute__((ext_vector_type(4)));
typedef _Float16 f16x8 __attribute__((ext_vector_type(8)));

// ---------------- k0: pack W1 (f32 [32][1024]) into f16 B-fragments (K=32) ----------------
// Entry idx = (ks*64 + lane)*4 + tile, 8 f16 each:
//   j=0..7: B[k][n], k = ks*32 + 8*(lane>>4) + j, n = tile*16 + (lane&15)
//   B[k][n] = W1[n&31][(n>>5)*512 + k]
__global__ __launch_bounds__(256) void k0_bfrag(const float* __restrict__ W1,
                                                _Float16* __restrict__ Bfrag) {
  int idx = blockIdx.x * 256 + threadIdx.x;
  if (idx >= KSTEPS32 * 64 * 4) return;
  int tile = idx & 3;
  int lane = (idx >> 2) & 63;
  int ks   = idx >> 8;
  int n = tile * 16 + (lane & 15);
  int kbase = ks * 32 + ((lane >> 4) << 3);
  const float* src = W1 + (size_t)(n & 31) * (2 * NFEAT) + (n >> 5) * NFEAT + kbase;
  _Float16* dst = Bfrag + (size_t)idx * 8;
#pragma unroll
  for (int j = 0; j < 8; ++j) dst[j] = (_Float16)src[j];
}

// ---------------- K1: PQ(f16) = feat @ Wr.T via 16x16x32 MFMA ----------------
// 256 threads = 4 waves; wave computes 32 rows x 64 cols; block = 128 rows.
__global__ __launch_bounds__(256) void k1_mfma(
    const float* __restrict__ feat, const _Float16* __restrict__ Bfrag,
    _Float16* __restrict__ PQ, int M) {
  __shared__ _Float16 sC[128][64];

  const int tid  = threadIdx.x;
  const int wave = tid >> 6;
  const int lane = tid & 63;
  const int g    = lane >> 4;
  const int r    = lane & 15;
  const int blockRow = blockIdx.x * 128;
  const int rowbase  = blockRow + wave * 32;

  int arow0 = rowbase + r;
  int arow1 = rowbase + 16 + r;
  if (arow0 >= M) arow0 = M - 1;     // clamp; stores guarded
  if (arow1 >= M) arow1 = M - 1;
  const float* ap0 = feat + (size_t)arow0 * NFEAT + (g << 3);
  const float* ap1 = feat + (size_t)arow1 * NFEAT + (g << 3);
  const _Float16* bp = Bfrag + (size_t)lane * 32;   // 4 tiles x 8 f16, contiguous

  f32x4 acc00 = {0.f,0.f,0.f,0.f}, acc01 = {0.f,0.f,0.f,0.f};
  f32x4 acc02 = {0.f,0.f,0.f,0.f}, acc03 = {0.f,0.f,0.f,0.f};
  f32x4 acc10 = {0.f,0.f,0.f,0.f}, acc11 = {0.f,0.f,0.f,0.f};
  f32x4 acc12 = {0.f,0.f,0.f,0.f}, acc13 = {0.f,0.f,0.f,0.f};

#pragma unroll 4
  for (int ks = 0; ks < KSTEPS32; ++ks) {
    // A: 8 consecutive floats per row-tile (full 128B line per row across the wave)
    f32x4 a0lo = __builtin_nontemporal_load((const f32x4*)(ap0 + ks * 32));
    f32x4 a0hi = __builtin_nontemporal_load((const f32x4*)(ap0 + ks * 32 + 4));
    f32x4 a1lo = __builtin_nontemporal_load((const f32x4*)(ap1 + ks * 32));
    f32x4 a1hi = __builtin_nontemporal_load((const f32x4*)(ap1 + ks * 32 + 4));

    const _Float16* bb = bp + (size_t)ks * 2048;    // 64 lanes x 32 f16 per ks
    f16x8 b0 = *(const f16x8*)(bb);
    f16x8 b1 = *(const f16x8*)(bb + 8);
    f16x8 b2 = *(const f16x8*)(bb + 16);
    f16x8 b3 = *(const f16x8*)(bb + 24);

    f16x8 a0, a1;
#pragma unroll
    for (int j = 0; j < 4; ++j) {
      a0[j]     = (_Float16)a0lo[j];
      a0[j + 4] = (_Float16)a0hi[j];
      a1[j]     = (_Float16)a1lo[j];
      a1[j + 4] = (_Float16)a1hi[j];
    }

    acc00 = __builtin_amdgcn_mfma_f32_16x16x32_f16(a0, b0, acc00, 0, 0, 0);
    acc01 = __builtin_amdgcn_mfma_f32_16x16x32_f16(a0, b1, acc01, 0, 0, 0);
    acc02 = __builtin_amdgcn_mfma_f32_16x16x32_f16(a0, b2, acc02, 0, 0, 0);
    acc03 = __builtin_amdgcn_mfma_f32_16x16x32_f16(a0, b3, acc03, 0, 0, 0);
    acc10 = __builtin_amdgcn_mfma_f32_16x16x32_f16(a1, b0, acc10, 0, 0, 0);
    acc11 = __builtin_amdgcn_mfma_f32_16x16x32_f16(a1, b1, acc11, 0, 0, 0);
    acc12 = __builtin_amdgcn_mfma_f32_16x16x32_f16(a1, b2, acc12, 0, 0, 0);
    acc13 = __builtin_amdgcn_mfma_f32_16x16x32_f16(a1, b3, acc13, 0, 0, 0);
  }

  // C layout per tile (verified, same as 16x16x16): row = 4g + reg (+16 for
  // second row-tile), col = t*16 + r.
  const int lr0 = wave * 32 + 4 * g;
#pragma unroll
  for (int rg = 0; rg < 4; ++rg) {
    sC[lr0 + rg     ][r     ] = (_Float16)acc00[rg];
    sC[lr0 + rg     ][r + 16] = (_Float16)acc01[rg];
    sC[lr0 + rg     ][r + 32] = (_Float16)acc02[rg];
    sC[lr0 + rg     ][r + 48] = (_Float16)acc03[rg];
    sC[lr0 + rg + 16][r     ] = (_Float16)acc10[rg];
    sC[lr0 + rg + 16][r + 16] = (_Float16)acc11[rg];
    sC[lr0 + rg + 16][r + 32] = (_Float16)acc12[rg];
    sC[lr0 + rg + 16][r + 48] = (_Float16)acc13[rg];
  }
  __syncthreads();

  const int srow = tid >> 1;
  const int half = (tid & 1) * 32;
  const int grow = blockRow + srow;
  if (grow < M) {
    _Float16* dst = PQ + (size_t)grow * NPQ + half;
    const _Float16* srcp = &sC[srow][half];
#pragma unroll
    for (int i = 0; i < 4; ++i)
      *(f16x8*)(dst + i * 8) = *(const f16x8*)(srcp + i * 8);
  }
}

// ---------------- K2: H1[i] = relu(P[i] + 0.2 * sum_s Q[neigh1[i][s]]) ----------------
__global__ __launch_bounds__(256) void k2_agg(
    const _Float16* __restrict__ PQ, const int* __restrict__ neigh1,
    _Float16* __restrict__ H1, int M) {
  int gid = blockIdx.x * 256 + threadIdx.x;
  if (gid >= M * 4) return;
  int i = gid >> 2;
  int q = gid & 3;

  f16x8 p = *(const f16x8*)(PQ + (size_t)i * NPQ + q * 8);
  float acc[8];
#pragma unroll
  for (int j = 0; j < 8; ++j) acc[j] = 0.f;
#pragma unroll
  for (int s = 0; s < SAMP; ++s) {
    int n = neigh1[i * SAMP + s];
    f16x8 v = *(const f16x8*)(PQ + (size_t)n * NPQ + HID + q * 8);
#pragma unroll
    for (int j = 0; j < 8; ++j) acc[j] += (float)v[j];
  }
  f16x8 rr;
#pragma unroll
  for (int j = 0; j < 8; ++j)
    rr[j] = (_Float16)fmaxf((float)p[j] + 0.2f * acc[j], 0.f);
  *(f16x8*)(H1 + (size_t)i * HID + q * 8) = rr;
}

// ---------------- K3: two-stage MFMA  out = relu(comb2@W2.T)@Wc.T ----------------
__global__ __launch_bounds__(256) void k3_mfma(
    const _Float16* __restrict__ H1, const float* __restrict__ W2,
    const float* __restrict__ Wc, const int* __restrict__ nodes,
    const int* __restrict__ neigh2, float* __restrict__ out, int B) {
  __shared__ _Float16 sC2[128][88];
  __shared__ _Float16 sH[4][32][40];

  const int tid  = threadIdx.x;
  const int wave = tid >> 6;
  const int lane = tid & 63;
  const int g    = lane >> 4;
  const int r    = lane & 15;
  const int blockRow = blockIdx.x * 128;

  // ---- gather comb2 = [H1[self] | 0.2*sum H1[neigh]] into sC2 ----
  {
    const int lr = tid >> 1;
    const int hf = tid & 1;
    int grow = blockRow + lr;
    if (grow >= B) grow = B - 1;
    const _Float16* hs = H1 + (size_t)nodes[grow] * HID + hf * 16;
    *(f16x8*)&sC2[lr][hf * 16]     = *(const f16x8*)hs;
    *(f16x8*)&sC2[lr][hf * 16 + 8] = *(const f16x8*)(hs + 8);

    float na[16];
#pragma unroll
    for (int j = 0; j < 16; ++j) na[j] = 0.f;
    const int* nb = neigh2 + (size_t)grow * SAMP;
#pragma unroll
    for (int s = 0; s < SAMP; ++s) {
      const _Float16* hn = H1 + (size_t)nb[s] * HID + hf * 16;
      f16x8 v0 = *(const f16x8*)hn;
      f16x8 v1 = *(const f16x8*)(hn + 8);
#pragma unroll
      for (int j = 0; j < 8; ++j) { na[j] += (float)v0[j]; na[8 + j] += (float)v1[j]; }
    }
    f16x8 w0, w1;
#pragma unroll
    for (int j = 0; j < 8; ++j) {
      w0[j] = (_Float16)(0.2f * na[j]);
      w1[j] = (_Float16)(0.2f * na[8 + j]);
    }
    *(f16x8*)&sC2[lr][32 + hf * 16]     = w0;
    *(f16x8*)&sC2[lr][32 + hf * 16 + 8] = w1;
  }

  // ---- W2 / Wc B-fragments (per-lane registers; L2-hot) ----
  f16x4 w2f[4][2];
#pragma unroll
  for (int ks = 0; ks < 4; ++ks)
#pragma unroll
    for (int t = 0; t < 2; ++t) {
      int n = t * 16 + r;
      float4 v = *(const float4*)(W2 + (size_t)n * (2 * HID) + ks * 16 + (g << 2));
      f16x4 f; f[0] = (_Float16)v.x; f[1] = (_Float16)v.y;
      f[2] = (_Float16)v.z; f[3] = (_Float16)v.w;
      w2f[ks][t] = f;
    }
  f16x4 wcf[2][3];
#pragma unroll
  for (int ks = 0; ks < 2; ++ks)
#pragma unroll
    for (int t = 0; t < 3; ++t) {
      int n = t * 16 + r;
      f16x4 f = {(_Float16)0.f, (_Float16)0.f, (_Float16)0.f, (_Float16)0.f};
      if (n < NCLS) {
        float4 v = *(const float4*)(Wc + (size_t)n * HID + ks * 16 + (g << 2));
        f[0] = (_Float16)v.x; f[1] = (_Float16)v.y;
        f[2] = (_Float16)v.z; f[3] = (_Float16)v.w;
      }
      wcf[ks][t] = f;
    }
  __syncthreads();

  // ---- stage 1: h2 = relu(comb2 @ W2.T), K=64, N=32 ----
  f32x4 a00 = {0.f,0.f,0.f,0.f}, a01 = {0.f,0.f,0.f,0.f};
  f32x4 a10 = {0.f,0.f,0.f,0.f}, a11 = {0.f,0.f,0.f,0.f};
  const int rb = wave * 32;
#pragma unroll
  for (int ks = 0; ks < 4; ++ks) {
    f16x4 v0 = *(const f16x4*)&sC2[rb + r][ks * 16 + (g << 2)];
    f16x4 v1 = *(const f16x4*)&sC2[rb + 16 + r][ks * 16 + (g << 2)];
    a00 = __builtin_amdgcn_mfma_f32_16x16x16f16(v0, w2f[ks][0], a00, 0, 0, 0);
    a01 = __builtin_amdgcn_mfma_f32_16x16x16f16(v0, w2f[ks][1], a01, 0, 0, 0);
    a10 = __builtin_amdgcn_mfma_f32_16x16x16f16(v1, w2f[ks][0], a10, 0, 0, 0);
    a11 = __builtin_amdgcn_mfma_f32_16x16x16f16(v1, w2f[ks][1], a11, 0, 0, 0);
  }
#pragma unroll
  for (int rg = 0; rg < 4; ++rg) {
    int row = 4 * g + rg;
    sH[wave][row][r]           = (_Float16)fmaxf(a00[rg], 0.f);
    sH[wave][row][r + 16]      = (_Float16)fmaxf(a01[rg], 0.f);
    sH[wave][row + 16][r]      = (_Float16)fmaxf(a10[rg], 0.f);
    sH[wave][row + 16][r + 16] = (_Float16)fmaxf(a11[rg], 0.f);
  }
  __syncthreads();

  // ---- stage 2: out = h2 @ Wc.T, K=32, N=40 (3 col-tiles, zero-padded) ----
  f32x4 o00 = {0.f,0.f,0.f,0.f}, o01 = {0.f,0.f,0.f,0.f}, o02 = {0.f,0.f,0.f,0.f};
  f32x4 o10 = {0.f,0.f,0.f,0.f}, o11 = {0.f,0.f,0.f,0.f}, o12 = {0.f,0.f,0.f,0.f};
#pragma unroll
  for (int ks = 0; ks < 2; ++ks) {
    f16x4 v0 = *(const f16x4*)&sH[wave][r][ks * 16 + (g << 2)];
    f16x4 v1 = *(const f16x4*)&sH[wave][16 + r][ks * 16 + (g << 2)];
    o00 = __builtin_amdgcn_mfma_f32_16x16x16f16(v0, wcf[ks][0], o00, 0, 0, 0);
    o01 = __builtin_amdgcn_mfma_f32_16x16x16f16(v0, wcf[ks][1], o01, 0, 0, 0);
    o02 = __builtin_amdgcn_mfma_f32_16x16x16f16(v0, wcf[ks][2], o02, 0, 0, 0);
    o10 = __builtin_amdgcn_mfma_f32_16x16x16f16(v1, wcf[ks][0], o10, 0, 0, 0);
    o11 = __builtin_amdgcn_mfma_f32_16x16x16f16(v1, wcf[ks][1], o11, 0, 0, 0);
    o12 = __builtin_amdgcn_mfma_f32_16x16x16f16(v1, wcf[ks][2], o12, 0, 0, 0);
  }
#pragma unroll
  for (int rg = 0; rg < 4; ++rg) {
    int row0 = blockRow + rb + 4 * g + rg;
    int row1 = row0 + 16;
    if (row0 < B) {
      float* ob = out + (size_t)row0 * NCLS;
      ob[r] = o00[rg];
      ob[r + 16] = o01[rg];
      if (r + 32 < NCLS) ob[r + 32] = o02[rg];
    }
    if (row1 < B) {
      float* ob = out + (size_t)row1 * NCLS;
      ob[r] = o10[rg];
      ob[r + 16] = o11[rg];
      if (r + 32 < NCLS) ob[r + 32] = o12[rg];
    }
  }
}

extern "C" void kernel_launch(void* const* d_in, const int* in_sizes, int n_in,
                              void* d_out, int out_size, void* d_ws, size_t ws_size,
                              hipStream_t stream) {
  const float* feat   = (const float*)d_in[0];
  const float* W1     = (const float*)d_in[1];
  const float* W2     = (const float*)d_in[2];
  const float* Wc     = (const float*)d_in[3];
  const int*   nodes  = (const int*)d_in[4];
  const int*   neigh1 = (const int*)d_in[5];
  const int*   neigh2 = (const int*)d_in[6];
  float* out = (float*)d_out;

  const int M = in_sizes[0] / NFEAT;   // 100000 nodes
  const int B = in_sizes[4];           // 16384 batch

  // workspace: Bfrag f16 [16*64*4*8] (64 KB), PQ f16 [M][64], H1 f16 [M][32]
  size_t bfrag_elems = (size_t)KSTEPS32 * 64 * 4 * 8;
  size_t need = (bfrag_elems + (size_t)M * NPQ + (size_t)M * HID) * sizeof(_Float16);
  if (ws_size < need) return;  // fail loudly (output stays poisoned)

  _Float16* Bfrag = (_Float16*)d_ws;
  _Float16* PQ = Bfrag + bfrag_elems;
  _Float16* H1 = PQ + (size_t)M * NPQ;

  k0_bfrag<<<(KSTEPS32 * 64 * 4 + 255) / 256, 256, 0, stream>>>(W1, Bfrag);
  k1_mfma<<<(M + 127) / 128, 256, 0, stream>>>(feat, Bfrag, PQ, M);
  k2_agg<<<(M * 4 + 255) / 256, 256, 0, stream>>>(PQ, neigh1, H1, M);
  k3_mfma<<<(B + 127) / 128, 256, 0, stream>>>(H1, W2, Wc, nodes, neigh2, out, B);
}

// Round 13
// 74.420 us; speedup vs baseline: 1.2302x; 1.2302x over previous
//
#include <hip/hip_runtime.h>
#include <hip/hip_bf16.h>

// SupervisedGraphSage forward via linearity of matmul-over-concat:
//   PQ[i][0:32]  = feat[i] @ W1[:, 0:512].T      (P)
//   PQ[i][32:64] = feat[i] @ W1[:, 512:1024].T   (Q)
//   H1[i] = relu(P[i] + 0.2 * sum_s Q[neigh1[i][s]])
//   comb2[b] = [H1[nodes[b]], 0.2 * sum_s H1[neigh2[b][s]]]
//   out[b] = relu(comb2 @ W2.T) @ Wc.T
//
// R12->R13: SINGLE-VARIABLE fix of R12's regression: nontemporal feat loads
// removed (they defeat the L3-warm replay regime: feat 205MB < 256MB L3;
// NT bypass/evict pushed k1 back to HBM => +21us). K=32 MFMA kept to isolate
// its effect with regular loads. Everything else byte-identical to R12.
// Ledger: R10=70.3 best; k1 target 42.7; NT-loads refuted; coop refuted.

#define NFEAT 512
#define NPQ   64
#define HID   32
#define NCLS  40
#define SAMP  5
#define KSTEPS32 (NFEAT / 32)   // 16

typedef float    f32x4 __attribute__((ext_vector_type(4)));
typedef _Float16 f16x4 __attribute__((ext_vector_type(4)));
typedef _Float16 f16x8 __attribute__((ext_vector_type(8)));

// ---------------- k0: pack W1 (f32 [32][1024]) into f16 B-fragments (K=32) ----------------
// Entry idx = (ks*64 + lane)*4 + tile, 8 f16 each:
//   j=0..7: B[k][n], k = ks*32 + 8*(lane>>4) + j, n = tile*16 + (lane&15)
//   B[k][n] = W1[n&31][(n>>5)*512 + k]
__global__ __launch_bounds__(256) void k0_bfrag(const float* __restrict__ W1,
                                                _Float16* __restrict__ Bfrag) {
  int idx = blockIdx.x * 256 + threadIdx.x;
  if (idx >= KSTEPS32 * 64 * 4) return;
  int tile = idx & 3;
  int lane = (idx >> 2) & 63;
  int ks   = idx >> 8;
  int n = tile * 16 + (lane & 15);
  int kbase = ks * 32 + ((lane >> 4) << 3);
  const float* src = W1 + (size_t)(n & 31) * (2 * NFEAT) + (n >> 5) * NFEAT + kbase;
  _Float16* dst = Bfrag + (size_t)idx * 8;
#pragma unroll
  for (int j = 0; j < 8; ++j) dst[j] = (_Float16)src[j];
}

// ---------------- K1: PQ(f16) = feat @ Wr.T via 16x16x32 MFMA ----------------
// 256 threads = 4 waves; wave computes 32 rows x 64 cols; block = 128 rows.
__global__ __launch_bounds__(256) void k1_mfma(
    const float* __restrict__ feat, const _Float16* __restrict__ Bfrag,
    _Float16* __restrict__ PQ, int M) {
  __shared__ _Float16 sC[128][64];

  const int tid  = threadIdx.x;
  const int wave = tid >> 6;
  const int lane = tid & 63;
  const int g    = lane >> 4;
  const int r    = lane & 15;
  const int blockRow = blockIdx.x * 128;
  const int rowbase  = blockRow + wave * 32;

  int arow0 = rowbase + r;
  int arow1 = rowbase + 16 + r;
  if (arow0 >= M) arow0 = M - 1;     // clamp; stores guarded
  if (arow1 >= M) arow1 = M - 1;
  const float* ap0 = feat + (size_t)arow0 * NFEAT + (g << 3);
  const float* ap1 = feat + (size_t)arow1 * NFEAT + (g << 3);
  const _Float16* bp = Bfrag + (size_t)lane * 32;   // 4 tiles x 8 f16, contiguous

  f32x4 acc00 = {0.f,0.f,0.f,0.f}, acc01 = {0.f,0.f,0.f,0.f};
  f32x4 acc02 = {0.f,0.f,0.f,0.f}, acc03 = {0.f,0.f,0.f,0.f};
  f32x4 acc10 = {0.f,0.f,0.f,0.f}, acc11 = {0.f,0.f,0.f,0.f};
  f32x4 acc12 = {0.f,0.f,0.f,0.f}, acc13 = {0.f,0.f,0.f,0.f};

#pragma unroll 4
  for (int ks = 0; ks < KSTEPS32; ++ks) {
    // A: 8 consecutive floats per row-tile (full 128B line per row across the wave)
    f32x4 a0lo = *(const f32x4*)(ap0 + ks * 32);
    f32x4 a0hi = *(const f32x4*)(ap0 + ks * 32 + 4);
    f32x4 a1lo = *(const f32x4*)(ap1 + ks * 32);
    f32x4 a1hi = *(const f32x4*)(ap1 + ks * 32 + 4);

    const _Float16* bb = bp + (size_t)ks * 2048;    // 64 lanes x 32 f16 per ks
    f16x8 b0 = *(const f16x8*)(bb);
    f16x8 b1 = *(const f16x8*)(bb + 8);
    f16x8 b2 = *(const f16x8*)(bb + 16);
    f16x8 b3 = *(const f16x8*)(bb + 24);

    f16x8 a0, a1;
#pragma unroll
    for (int j = 0; j < 4; ++j) {
      a0[j]     = (_Float16)a0lo[j];
      a0[j + 4] = (_Float16)a0hi[j];
      a1[j]     = (_Float16)a1lo[j];
      a1[j + 4] = (_Float16)a1hi[j];
    }

    acc00 = __builtin_amdgcn_mfma_f32_16x16x32_f16(a0, b0, acc00, 0, 0, 0);
    acc01 = __builtin_amdgcn_mfma_f32_16x16x32_f16(a0, b1, acc01, 0, 0, 0);
    acc02 = __builtin_amdgcn_mfma_f32_16x16x32_f16(a0, b2, acc02, 0, 0, 0);
    acc03 = __builtin_amdgcn_mfma_f32_16x16x32_f16(a0, b3, acc03, 0, 0, 0);
    acc10 = __builtin_amdgcn_mfma_f32_16x16x32_f16(a1, b0, acc10, 0, 0, 0);
    acc11 = __builtin_amdgcn_mfma_f32_16x16x32_f16(a1, b1, acc11, 0, 0, 0);
    acc12 = __builtin_amdgcn_mfma_f32_16x16x32_f16(a1, b2, acc12, 0, 0, 0);
    acc13 = __builtin_amdgcn_mfma_f32_16x16x32_f16(a1, b3, acc13, 0, 0, 0);
  }

  // C layout per tile (verified, same as 16x16x16): row = 4g + reg (+16 for
  // second row-tile), col = t*16 + r.
  const int lr0 = wave * 32 + 4 * g;
#pragma unroll
  for (int rg = 0; rg < 4; ++rg) {
    sC[lr0 + rg     ][r     ] = (_Float16)acc00[rg];
    sC[lr0 + rg     ][r + 16] = (_Float16)acc01[rg];
    sC[lr0 + rg     ][r + 32] = (_Float16)acc02[rg];
    sC[lr0 + rg     ][r + 48] = (_Float16)acc03[rg];
    sC[lr0 + rg + 16][r     ] = (_Float16)acc10[rg];
    sC[lr0 + rg + 16][r + 16] = (_Float16)acc11[rg];
    sC[lr0 + rg + 16][r + 32] = (_Float16)acc12[rg];
    sC[lr0 + rg + 16][r + 48] = (_Float16)acc13[rg];
  }
  __syncthreads();

  const int srow = tid >> 1;
  const int half = (tid & 1) * 32;
  const int grow = blockRow + srow;
  if (grow < M) {
    _Float16* dst = PQ + (size_t)grow * NPQ + half;
    const _Float16* srcp = &sC[srow][half];
#pragma unroll
    for (int i = 0; i < 4; ++i)
      *(f16x8*)(dst + i * 8) = *(const f16x8*)(srcp + i * 8);
  }
}

// ---------------- K2: H1[i] = relu(P[i] + 0.2 * sum_s Q[neigh1[i][s]]) ----------------
__global__ __launch_bounds__(256) void k2_agg(
    const _Float16* __restrict__ PQ, const int* __restrict__ neigh1,
    _Float16* __restrict__ H1, int M) {
  int gid = blockIdx.x * 256 + threadIdx.x;
  if (gid >= M * 4) return;
  int i = gid >> 2;
  int q = gid & 3;

  f16x8 p = *(const f16x8*)(PQ + (size_t)i * NPQ + q * 8);
  float acc[8];
#pragma unroll
  for (int j = 0; j < 8; ++j) acc[j] = 0.f;
#pragma unroll
  for (int s = 0; s < SAMP; ++s) {
    int n = neigh1[i * SAMP + s];
    f16x8 v = *(const f16x8*)(PQ + (size_t)n * NPQ + HID + q * 8);
#pragma unroll
    for (int j = 0; j < 8; ++j) acc[j] += (float)v[j];
  }
  f16x8 rr;
#pragma unroll
  for (int j = 0; j < 8; ++j)
    rr[j] = (_Float16)fmaxf((float)p[j] + 0.2f * acc[j], 0.f);
  *(f16x8*)(H1 + (size_t)i * HID + q * 8) = rr;
}

// ---------------- K3: two-stage MFMA  out = relu(comb2@W2.T)@Wc.T ----------------
__global__ __launch_bounds__(256) void k3_mfma(
    const _Float16* __restrict__ H1, const float* __restrict__ W2,
    const float* __restrict__ Wc, const int* __restrict__ nodes,
    const int* __restrict__ neigh2, float* __restrict__ out, int B) {
  __shared__ _Float16 sC2[128][88];
  __shared__ _Float16 sH[4][32][40];

  const int tid  = threadIdx.x;
  const int wave = tid >> 6;
  const int lane = tid & 63;
  const int g    = lane >> 4;
  const int r    = lane & 15;
  const int blockRow = blockIdx.x * 128;

  // ---- gather comb2 = [H1[self] | 0.2*sum H1[neigh]] into sC2 ----
  {
    const int lr = tid >> 1;
    const int hf = tid & 1;
    int grow = blockRow + lr;
    if (grow >= B) grow = B - 1;
    const _Float16* hs = H1 + (size_t)nodes[grow] * HID + hf * 16;
    *(f16x8*)&sC2[lr][hf * 16]     = *(const f16x8*)hs;
    *(f16x8*)&sC2[lr][hf * 16 + 8] = *(const f16x8*)(hs + 8);

    float na[16];
#pragma unroll
    for (int j = 0; j < 16; ++j) na[j] = 0.f;
    const int* nb = neigh2 + (size_t)grow * SAMP;
#pragma unroll
    for (int s = 0; s < SAMP; ++s) {
      const _Float16* hn = H1 + (size_t)nb[s] * HID + hf * 16;
      f16x8 v0 = *(const f16x8*)hn;
      f16x8 v1 = *(const f16x8*)(hn + 8);
#pragma unroll
      for (int j = 0; j < 8; ++j) { na[j] += (float)v0[j]; na[8 + j] += (float)v1[j]; }
    }
    f16x8 w0, w1;
#pragma unroll
    for (int j = 0; j < 8; ++j) {
      w0[j] = (_Float16)(0.2f * na[j]);
      w1[j] = (_Float16)(0.2f * na[8 + j]);
    }
    *(f16x8*)&sC2[lr][32 + hf * 16]     = w0;
    *(f16x8*)&sC2[lr][32 + hf * 16 + 8] = w1;
  }

  // ---- W2 / Wc B-fragments (per-lane registers; L2-hot) ----
  f16x4 w2f[4][2];
#pragma unroll
  for (int ks = 0; ks < 4; ++ks)
#pragma unroll
    for (int t = 0; t < 2; ++t) {
      int n = t * 16 + r;
      float4 v = *(const float4*)(W2 + (size_t)n * (2 * HID) + ks * 16 + (g << 2));
      f16x4 f; f[0] = (_Float16)v.x; f[1] = (_Float16)v.y;
      f[2] = (_Float16)v.z; f[3] = (_Float16)v.w;
      w2f[ks][t] = f;
    }
  f16x4 wcf[2][3];
#pragma unroll
  for (int ks = 0; ks < 2; ++ks)
#pragma unroll
    for (int t = 0; t < 3; ++t) {
      int n = t * 16 + r;
      f16x4 f = {(_Float16)0.f, (_Float16)0.f, (_Float16)0.f, (_Float16)0.f};
      if (n < NCLS) {
        float4 v = *(const float4*)(Wc + (size_t)n * HID + ks * 16 + (g << 2));
        f[0] = (_Float16)v.x; f[1] = (_Float16)v.y;
        f[2] = (_Float16)v.z; f[3] = (_Float16)v.w;
      }
      wcf[ks][t] = f;
    }
  __syncthreads();

  // ---- stage 1: h2 = relu(comb2 @ W2.T), K=64, N=32 ----
  f32x4 a00 = {0.f,0.f,0.f,0.f}, a01 = {0.f,0.f,0.f,0.f};
  f32x4 a10 = {0.f,0.f,0.f,0.f}, a11 = {0.f,0.f,0.f,0.f};
  const int rb = wave * 32;
#pragma unroll
  for (int ks = 0; ks < 4; ++ks) {
    f16x4 v0 = *(const f16x4*)&sC2[rb + r][ks * 16 + (g << 2)];
    f16x4 v1 = *(const f16x4*)&sC2[rb + 16 + r][ks * 16 + (g << 2)];
    a00 = __builtin_amdgcn_mfma_f32_16x16x16f16(v0, w2f[ks][0], a00, 0, 0, 0);
    a01 = __builtin_amdgcn_mfma_f32_16x16x16f16(v0, w2f[ks][1], a01, 0, 0, 0);
    a10 = __builtin_amdgcn_mfma_f32_16x16x16f16(v1, w2f[ks][0], a10, 0, 0, 0);
    a11 = __builtin_amdgcn_mfma_f32_16x16x16f16(v1, w2f[ks][1], a11, 0, 0, 0);
  }
#pragma unroll
  for (int rg = 0; rg < 4; ++rg) {
    int row = 4 * g + rg;
    sH[wave][row][r]           = (_Float16)fmaxf(a00[rg], 0.f);
    sH[wave][row][r + 16]      = (_Float16)fmaxf(a01[rg], 0.f);
    sH[wave][row + 16][r]      = (_Float16)fmaxf(a10[rg], 0.f);
    sH[wave][row + 16][r + 16] = (_Float16)fmaxf(a11[rg], 0.f);
  }
  __syncthreads();

  // ---- stage 2: out = h2 @ Wc.T, K=32, N=40 (3 col-tiles, zero-padded) ----
  f32x4 o00 = {0.f,0.f,0.f,0.f}, o01 = {0.f,0.f,0.f,0.f}, o02 = {0.f,0.f,0.f,0.f};
  f32x4 o10 = {0.f,0.f,0.f,0.f}, o11 = {0.f,0.f,0.f,0.f}, o12 = {0.f,0.f,0.f,0.f};
#pragma unroll
  for (int ks = 0; ks < 2; ++ks) {
    f16x4 v0 = *(const f16x4*)&sH[wave][r][ks * 16 + (g << 2)];
    f16x4 v1 = *(const f16x4*)&sH[wave][16 + r][ks * 16 + (g << 2)];
    o00 = __builtin_amdgcn_mfma_f32_16x16x16f16(v0, wcf[ks][0], o00, 0, 0, 0);
    o01 = __builtin_amdgcn_mfma_f32_16x16x16f16(v0, wcf[ks][1], o01, 0, 0, 0);
    o02 = __builtin_amdgcn_mfma_f32_16x16x16f16(v0, wcf[ks][2], o02, 0, 0, 0);
    o10 = __builtin_amdgcn_mfma_f32_16x16x16f16(v1, wcf[ks][0], o10, 0, 0, 0);
    o11 = __builtin_amdgcn_mfma_f32_16x16x16f16(v1, wcf[ks][1], o11, 0, 0, 0);
    o12 = __builtin_amdgcn_mfma_f32_16x16x16f16(v1, wcf[ks][2], o12, 0, 0, 0);
  }
#pragma unroll
  for (int rg = 0; rg < 4; ++rg) {
    int row0 = blockRow + rb + 4 * g + rg;
    int row1 = row0 + 16;
    if (row0 < B) {
      float* ob = out + (size_t)row0 * NCLS;
      ob[r] = o00[rg];
      ob[r + 16] = o01[rg];
      if (r + 32 < NCLS) ob[r + 32] = o02[rg];
    }
    if (row1 < B) {
      float* ob = out + (size_t)row1 * NCLS;
      ob[r] = o10[rg];
      ob[r + 16] = o11[rg];
      if (r + 32 < NCLS) ob[r + 32] = o12[rg];
    }
  }
}

extern "C" void kernel_launch(void* const* d_in, const int* in_sizes, int n_in,
                              void* d_out, int out_size, void* d_ws, size_t ws_size,
                              hipStream_t stream) {
  const float* feat   = (const float*)d_in[0];
  const float* W1     = (const float*)d_in[1];
  const float* W2     = (const float*)d_in[2];
  const float* Wc     = (const float*)d_in[3];
  const int*   nodes  = (const int*)d_in[4];
  const int*   neigh1 = (const int*)d_in[5];
  const int*   neigh2 = (const int*)d_in[6];
  float* out = (float*)d_out;

  const int M = in_sizes[0] / NFEAT;   // 100000 nodes
  const int B = in_sizes[4];           // 16384 batch

  // workspace: Bfrag f16 [16*64*4*8] (64 KB), PQ f16 [M][64], H1 f16 [M][32]
  size_t bfrag_elems = (size_t)KSTEPS32 * 64 * 4 * 8;
  size_t need = (bfrag_elems + (size_t)M * NPQ + (size_t)M * HID) * sizeof(_Float16);
  if (ws_size < need) return;  // fail loudly (output stays poisoned)

  _Float16* Bfrag = (_Float16*)d_ws;
  _Float16* PQ = Bfrag + bfrag_elems;
  _Float16* H1 = PQ + (size_t)M * NPQ;

  k0_bfrag<<<(KSTEPS32 * 64 * 4 + 255) / 256, 256, 0, stream>>>(W1, Bfrag);
  k1_mfma<<<(M + 127) / 128, 256, 0, stream>>>(feat, Bfrag, PQ, M);
  k2_agg<<<(M * 4 + 255) / 256, 256, 0, stream>>>(PQ, neigh1, H1, M);
  k3_mfma<<<(B + 127) / 128, 256, 0, stream>>>(H1, W2, Wc, nodes, neigh2, out, B);
}

// Round 14
// 70.188 us; speedup vs baseline: 1.3044x; 1.0603x over previous
//
#include <hip/hip_runtime.h>
#include <hip/hip_bf16.h>

// SupervisedGraphSage forward via linearity of matmul-over-concat:
//   PQ[i][0:32]  = feat[i] @ W1[:, 0:512].T      (P)
//   PQ[i][32:64] = feat[i] @ W1[:, 512:1024].T   (Q)
//   H1[i] = relu(P[i] + 0.2 * sum_s Q[neigh1[i][s]])
//   comb2[b] = [H1[nodes[b]], 0.2 * sum_s H1[neigh2[b][s]]]
//   out[b] = relu(comb2 @ W2.T) @ Wc.T
//
// R13->R14: REVERT to exact R10 configuration (best: 70.3us).
// Falsified on k1 (42.7us, L3-stream floor): B-traffic halving (R3/R8),
// coalesced epilogue (R4), prefetch+launch_bounds (R11), NT loads (R12, -17us
// regression: L3-warm replay regime), K=32 MFMA (R13, -4us: longer dep chains).
// Coop fusion refuted (R7/R9). k0~1.5, k2~1-2, k3_mfma~2-3, replay ~22 structural.

#define NFEAT 512
#define NPQ   64
#define HID   32
#define NCLS  40
#define SAMP  5
#define KSTEPS (NFEAT / 16)   // 32

typedef float    f32x4 __attribute__((ext_vector_type(4)));
typedef _Float16 f16x4 __attribute__((ext_vector_type(4)));
typedef _Float16 f16x8 __attribute__((ext_vector_type(8)));

// ---------------- k0: pack W1 (f32 [32][1024]) into f16 B-fragments ----------------
// Bfrag[((kstep*64 + lane)*4 + tile)*4 + j]; B[k][n] = W1[n&31][(n>>5)*512 + k]
__global__ __launch_bounds__(256) void k0_bfrag(const float* __restrict__ W1,
                                                _Float16* __restrict__ Bfrag) {
  int idx = blockIdx.x * 256 + threadIdx.x;
  if (idx >= KSTEPS * 64 * 4) return;
  int tile  = idx & 3;
  int lane  = (idx >> 2) & 63;
  int kstep = idx >> 8;
  int n = tile * 16 + (lane & 15);
  int kbase = kstep * 16 + ((lane >> 4) << 2);
  const float* src = W1 + (size_t)(n & 31) * (2 * NFEAT) + (n >> 5) * NFEAT + kbase;
  _Float16* dst = Bfrag + (size_t)idx * 4;
#pragma unroll
  for (int j = 0; j < 4; ++j) dst[j] = (_Float16)src[j];
}

// ---------------- K1: PQ(f16) = feat @ Wr.T via 16x16x16 MFMA ----------------
// 256 threads = 4 waves; wave computes 32 rows x 64 cols; block = 128 rows.
__global__ __launch_bounds__(256) void k1_mfma(
    const float* __restrict__ feat, const _Float16* __restrict__ Bfrag,
    _Float16* __restrict__ PQ, int M) {
  __shared__ _Float16 sC[128][64];

  const int tid  = threadIdx.x;
  const int wave = tid >> 6;
  const int lane = tid & 63;
  const int g    = lane >> 4;
  const int r    = lane & 15;
  const int blockRow = blockIdx.x * 128;
  const int rowbase  = blockRow + wave * 32;

  int arow0 = rowbase + r;
  int arow1 = rowbase + 16 + r;
  if (arow0 >= M) arow0 = M - 1;     // clamp; stores guarded
  if (arow1 >= M) arow1 = M - 1;
  const float* ap0 = feat + (size_t)arow0 * NFEAT + (g << 2);
  const float* ap1 = feat + (size_t)arow1 * NFEAT + (g << 2);
  const _Float16* bp = Bfrag + (size_t)lane * 16;

  f32x4 acc00 = {0.f,0.f,0.f,0.f}, acc01 = {0.f,0.f,0.f,0.f};
  f32x4 acc02 = {0.f,0.f,0.f,0.f}, acc03 = {0.f,0.f,0.f,0.f};
  f32x4 acc10 = {0.f,0.f,0.f,0.f}, acc11 = {0.f,0.f,0.f,0.f};
  f32x4 acc12 = {0.f,0.f,0.f,0.f}, acc13 = {0.f,0.f,0.f,0.f};

#pragma unroll 4
  for (int ks = 0; ks < KSTEPS; ++ks) {
    float4 av0 = *(const float4*)(ap0 + ks * 16);
    float4 av1 = *(const float4*)(ap1 + ks * 16);
    f16x4 a0, a1;
    a0[0] = (_Float16)av0.x; a0[1] = (_Float16)av0.y;
    a0[2] = (_Float16)av0.z; a0[3] = (_Float16)av0.w;
    a1[0] = (_Float16)av1.x; a1[1] = (_Float16)av1.y;
    a1[2] = (_Float16)av1.z; a1[3] = (_Float16)av1.w;
    const _Float16* bb = bp + (size_t)ks * 1024;
    f16x8 b01 = *(const f16x8*)bb;
    f16x8 b23 = *(const f16x8*)(bb + 8);
    f16x4 b0 = __builtin_shufflevector(b01, b01, 0, 1, 2, 3);
    f16x4 b1 = __builtin_shufflevector(b01, b01, 4, 5, 6, 7);
    f16x4 b2 = __builtin_shufflevector(b23, b23, 0, 1, 2, 3);
    f16x4 b3 = __builtin_shufflevector(b23, b23, 4, 5, 6, 7);
    acc00 = __builtin_amdgcn_mfma_f32_16x16x16f16(a0, b0, acc00, 0, 0, 0);
    acc01 = __builtin_amdgcn_mfma_f32_16x16x16f16(a0, b1, acc01, 0, 0, 0);
    acc02 = __builtin_amdgcn_mfma_f32_16x16x16f16(a0, b2, acc02, 0, 0, 0);
    acc03 = __builtin_amdgcn_mfma_f32_16x16x16f16(a0, b3, acc03, 0, 0, 0);
    acc10 = __builtin_amdgcn_mfma_f32_16x16x16f16(a1, b0, acc10, 0, 0, 0);
    acc11 = __builtin_amdgcn_mfma_f32_16x16x16f16(a1, b1, acc11, 0, 0, 0);
    acc12 = __builtin_amdgcn_mfma_f32_16x16x16f16(a1, b2, acc12, 0, 0, 0);
    acc13 = __builtin_amdgcn_mfma_f32_16x16x16f16(a1, b3, acc13, 0, 0, 0);
  }

  // C layout per tile: row = 4g + reg (+ rt*16), col = t*16 + r.
  const int lr0 = wave * 32 + 4 * g;
#pragma unroll
  for (int rg = 0; rg < 4; ++rg) {
    sC[lr0 + rg     ][r     ] = (_Float16)acc00[rg];
    sC[lr0 + rg     ][r + 16] = (_Float16)acc01[rg];
    sC[lr0 + rg     ][r + 32] = (_Float16)acc02[rg];
    sC[lr0 + rg     ][r + 48] = (_Float16)acc03[rg];
    sC[lr0 + rg + 16][r     ] = (_Float16)acc10[rg];
    sC[lr0 + rg + 16][r + 16] = (_Float16)acc11[rg];
    sC[lr0 + rg + 16][r + 32] = (_Float16)acc12[rg];
    sC[lr0 + rg + 16][r + 48] = (_Float16)acc13[rg];
  }
  __syncthreads();

  const int srow = tid >> 1;
  const int half = (tid & 1) * 32;
  const int grow = blockRow + srow;
  if (grow < M) {
    _Float16* dst = PQ + (size_t)grow * NPQ + half;
    const _Float16* srcp = &sC[srow][half];
#pragma unroll
    for (int i = 0; i < 4; ++i)
      *(f16x8*)(dst + i * 8) = *(const f16x8*)(srcp + i * 8);
  }
}

// ---------------- K2: H1[i] = relu(P[i] + 0.2 * sum_s Q[neigh1[i][s]]) ----------------
__global__ __launch_bounds__(256) void k2_agg(
    const _Float16* __restrict__ PQ, const int* __restrict__ neigh1,
    _Float16* __restrict__ H1, int M) {
  int gid = blockIdx.x * 256 + threadIdx.x;
  if (gid >= M * 4) return;
  int i = gid >> 2;
  int q = gid & 3;

  f16x8 p = *(const f16x8*)(PQ + (size_t)i * NPQ + q * 8);
  float acc[8];
#pragma unroll
  for (int j = 0; j < 8; ++j) acc[j] = 0.f;
#pragma unroll
  for (int s = 0; s < SAMP; ++s) {
    int n = neigh1[i * SAMP + s];
    f16x8 v = *(const f16x8*)(PQ + (size_t)n * NPQ + HID + q * 8);
#pragma unroll
    for (int j = 0; j < 8; ++j) acc[j] += (float)v[j];
  }
  f16x8 rr;
#pragma unroll
  for (int j = 0; j < 8; ++j)
    rr[j] = (_Float16)fmaxf((float)p[j] + 0.2f * acc[j], 0.f);
  *(f16x8*)(H1 + (size_t)i * HID + q * 8) = rr;
}

// ---------------- K3: two-stage MFMA  out = relu(comb2@W2.T)@Wc.T ----------------
__global__ __launch_bounds__(256) void k3_mfma(
    const _Float16* __restrict__ H1, const float* __restrict__ W2,
    const float* __restrict__ Wc, const int* __restrict__ nodes,
    const int* __restrict__ neigh2, float* __restrict__ out, int B) {
  __shared__ _Float16 sC2[128][88];
  __shared__ _Float16 sH[4][32][40];

  const int tid  = threadIdx.x;
  const int wave = tid >> 6;
  const int lane = tid & 63;
  const int g    = lane >> 4;
  const int r    = lane & 15;
  const int blockRow = blockIdx.x * 128;

  // ---- gather comb2 = [H1[self] | 0.2*sum H1[neigh]] into sC2 ----
  {
    const int lr = tid >> 1;
    const int hf = tid & 1;
    int grow = blockRow + lr;
    if (grow >= B) grow = B - 1;
    const _Float16* hs = H1 + (size_t)nodes[grow] * HID + hf * 16;
    *(f16x8*)&sC2[lr][hf * 16]     = *(const f16x8*)hs;
    *(f16x8*)&sC2[lr][hf * 16 + 8] = *(const f16x8*)(hs + 8);

    float na[16];
#pragma unroll
    for (int j = 0; j < 16; ++j) na[j] = 0.f;
    const int* nb = neigh2 + (size_t)grow * SAMP;
#pragma unroll
    for (int s = 0; s < SAMP; ++s) {
      const _Float16* hn = H1 + (size_t)nb[s] * HID + hf * 16;
      f16x8 v0 = *(const f16x8*)hn;
      f16x8 v1 = *(const f16x8*)(hn + 8);
#pragma unroll
      for (int j = 0; j < 8; ++j) { na[j] += (float)v0[j]; na[8 + j] += (float)v1[j]; }
    }
    f16x8 w0, w1;
#pragma unroll
    for (int j = 0; j < 8; ++j) {
      w0[j] = (_Float16)(0.2f * na[j]);
      w1[j] = (_Float16)(0.2f * na[8 + j]);
    }
    *(f16x8*)&sC2[lr][32 + hf * 16]     = w0;
    *(f16x8*)&sC2[lr][32 + hf * 16 + 8] = w1;
  }

  // ---- W2 / Wc B-fragments (per-lane registers; L2-hot) ----
  f16x4 w2f[4][2];
#pragma unroll
  for (int ks = 0; ks < 4; ++ks)
#pragma unroll
    for (int t = 0; t < 2; ++t) {
      int n = t * 16 + r;
      float4 v = *(const float4*)(W2 + (size_t)n * (2 * HID) + ks * 16 + (g << 2));
      f16x4 f; f[0] = (_Float16)v.x; f[1] = (_Float16)v.y;
      f[2] = (_Float16)v.z; f[3] = (_Float16)v.w;
      w2f[ks][t] = f;
    }
  f16x4 wcf[2][3];
#pragma unroll
  for (int ks = 0; ks < 2; ++ks)
#pragma unroll
    for (int t = 0; t < 3; ++t) {
      int n = t * 16 + r;
      f16x4 f = {(_Float16)0.f, (_Float16)0.f, (_Float16)0.f, (_Float16)0.f};
      if (n < NCLS) {
        float4 v = *(const float4*)(Wc + (size_t)n * HID + ks * 16 + (g << 2));
        f[0] = (_Float16)v.x; f[1] = (_Float16)v.y;
        f[2] = (_Float16)v.z; f[3] = (_Float16)v.w;
      }
      wcf[ks][t] = f;
    }
  __syncthreads();

  // ---- stage 1: h2 = relu(comb2 @ W2.T), K=64, N=32 ----
  f32x4 a00 = {0.f,0.f,0.f,0.f}, a01 = {0.f,0.f,0.f,0.f};
  f32x4 a10 = {0.f,0.f,0.f,0.f}, a11 = {0.f,0.f,0.f,0.f};
  const int rb = wave * 32;
#pragma unroll
  for (int ks = 0; ks < 4; ++ks) {
    f16x4 v0 = *(const f16x4*)&sC2[rb + r][ks * 16 + (g << 2)];
    f16x4 v1 = *(const f16x4*)&sC2[rb + 16 + r][ks * 16 + (g << 2)];
    a00 = __builtin_amdgcn_mfma_f32_16x16x16f16(v0, w2f[ks][0], a00, 0, 0, 0);
    a01 = __builtin_amdgcn_mfma_f32_16x16x16f16(v0, w2f[ks][1], a01, 0, 0, 0);
    a10 = __builtin_amdgcn_mfma_f32_16x16x16f16(v1, w2f[ks][0], a10, 0, 0, 0);
    a11 = __builtin_amdgcn_mfma_f32_16x16x16f16(v1, w2f[ks][1], a11, 0, 0, 0);
  }
#pragma unroll
  for (int rg = 0; rg < 4; ++rg) {
    int row = 4 * g + rg;
    sH[wave][row][r]           = (_Float16)fmaxf(a00[rg], 0.f);
    sH[wave][row][r + 16]      = (_Float16)fmaxf(a01[rg], 0.f);
    sH[wave][row + 16][r]      = (_Float16)fmaxf(a10[rg], 0.f);
    sH[wave][row + 16][r + 16] = (_Float16)fmaxf(a11[rg], 0.f);
  }
  __syncthreads();

  // ---- stage 2: out = h2 @ Wc.T, K=32, N=40 (3 col-tiles, zero-padded) ----
  f32x4 o00 = {0.f,0.f,0.f,0.f}, o01 = {0.f,0.f,0.f,0.f}, o02 = {0.f,0.f,0.f,0.f};
  f32x4 o10 = {0.f,0.f,0.f,0.f}, o11 = {0.f,0.f,0.f,0.f}, o12 = {0.f,0.f,0.f,0.f};
#pragma unroll
  for (int ks = 0; ks < 2; ++ks) {
    f16x4 v0 = *(const f16x4*)&sH[wave][r][ks * 16 + (g << 2)];
    f16x4 v1 = *(const f16x4*)&sH[wave][16 + r][ks * 16 + (g << 2)];
    o00 = __builtin_amdgcn_mfma_f32_16x16x16f16(v0, wcf[ks][0], o00, 0, 0, 0);
    o01 = __builtin_amdgcn_mfma_f32_16x16x16f16(v0, wcf[ks][1], o01, 0, 0, 0);
    o02 = __builtin_amdgcn_mfma_f32_16x16x16f16(v0, wcf[ks][2], o02, 0, 0, 0);
    o10 = __builtin_amdgcn_mfma_f32_16x16x16f16(v1, wcf[ks][0], o10, 0, 0, 0);
    o11 = __builtin_amdgcn_mfma_f32_16x16x16f16(v1, wcf[ks][1], o11, 0, 0, 0);
    o12 = __builtin_amdgcn_mfma_f32_16x16x16f16(v1, wcf[ks][2], o12, 0, 0, 0);
  }
#pragma unroll
  for (int rg = 0; rg < 4; ++rg) {
    int row0 = blockRow + rb + 4 * g + rg;
    int row1 = row0 + 16;
    if (row0 < B) {
      float* ob = out + (size_t)row0 * NCLS;
      ob[r] = o00[rg];
      ob[r + 16] = o01[rg];
      if (r + 32 < NCLS) ob[r + 32] = o02[rg];
    }
    if (row1 < B) {
      float* ob = out + (size_t)row1 * NCLS;
      ob[r] = o10[rg];
      ob[r + 16] = o11[rg];
      if (r + 32 < NCLS) ob[r + 32] = o12[rg];
    }
  }
}

extern "C" void kernel_launch(void* const* d_in, const int* in_sizes, int n_in,
                              void* d_out, int out_size, void* d_ws, size_t ws_size,
                              hipStream_t stream) {
  const float* feat   = (const float*)d_in[0];
  const float* W1     = (const float*)d_in[1];
  const float* W2     = (const float*)d_in[2];
  const float* Wc     = (const float*)d_in[3];
  const int*   nodes  = (const int*)d_in[4];
  const int*   neigh1 = (const int*)d_in[5];
  const int*   neigh2 = (const int*)d_in[6];
  float* out = (float*)d_out;

  const int M = in_sizes[0] / NFEAT;   // 100000 nodes
  const int B = in_sizes[4];           // 16384 batch

  // workspace: Bfrag f16 [32*64*4*4] (64 KB), PQ f16 [M][64], H1 f16 [M][32]
  size_t bfrag_elems = (size_t)KSTEPS * 64 * 4 * 4;
  size_t need = (bfrag_elems + (size_t)M * NPQ + (size_t)M * HID) * sizeof(_Float16);
  if (ws_size < need) return;  // fail loudly (output stays poisoned)

  _Float16* Bfrag = (_Float16*)d_ws;
  _Float16* PQ = Bfrag + bfrag_elems;
  _Float16* H1 = PQ + (size_t)M * NPQ;

  k0_bfrag<<<(KSTEPS * 64 * 4 + 255) / 256, 256, 0, stream>>>(W1, Bfrag);
  k1_mfma<<<(M + 127) / 128, 256, 0, stream>>>(feat, Bfrag, PQ, M);
  k2_agg<<<(M * 4 + 255) / 256, 256, 0, stream>>>(PQ, neigh1, H1, M);
  k3_mfma<<<(B + 127) / 128, 256, 0, stream>>>(H1, W2, Wc, nodes, neigh2, out, B);
}